// Round 5
// baseline (7277.003 us; speedup 1.0000x reference)
//
#include <hip/hip_runtime.h>
#include <hip/hip_bf16.h>
#include <math.h>

#define BB 64
#define IMG 224
#define PP 16
#define CIN 3
#define DM 192
#define DEPTH 24
#define DSTATE 16
#define DINNER 384
#define DTR 12
#define DCONV 4
#define NP 196              // (224/16)^2
#define RTOT (BB * NP)      // 12544 rows
#define CHUNKS 7
#define LC 28               // NP / CHUNKS

// ---------------- im2col for patch embed ----------------
__global__ __launch_bounds__(256) void im2col_kernel(const float* __restrict__ img,
                                                     float* __restrict__ col) {
    size_t idx = (size_t)blockIdx.x * 256 + threadIdx.x;
    if (idx >= (size_t)RTOT * 768) return;
    int t = (int)(idx % 768);
    size_t r = idx / 768;
    int l = (int)(r % NP);
    int b = (int)(r / NP);
    int ph = l / 14, pw = l % 14;
    int ci = t / 256, rem = t % 256;
    int i = rem / 16, j = rem % 16;
    col[idx] = img[(((size_t)b * CIN + ci) * IMG + ph * 16 + i) * IMG + pw * 16 + j];
}

// ---------------- tiled fp32 GEMM with optional split-K ----------------
// C[M,N] = A[M,K](lda) * B[N,K]^T. blockIdx.z = K-split slice of length Kc.
// gridDim.z == 1: write C directly (+bias). gridDim.z > 1: write partial z at
// Cout + z*M*N (bias applied by reduce kernel). M%BM==0, Kc%16==0, N%4==0.
template<int BM, int BN, int RM, int RN>
__global__ __launch_bounds__(256) void gemm_tile_kernel(const float* __restrict__ A, int lda,
                                                        const float* __restrict__ Bm,
                                                        float* __restrict__ C,
                                                        const float* __restrict__ bias,
                                                        int M, int N, int K, int Kc) {
    constexpr int BK = 16;
    constexpr int LDA_S = BM + 4;
    constexpr int LDB_S = BN + 4;
    __shared__ float As[BK * LDA_S];
    __shared__ float Bs[BK * LDB_S];
    const int tid = threadIdx.x;
    const int tr = tid / 16, tc = tid % 16;
    const int row0 = blockIdx.y * BM, col0 = blockIdx.x * BN;
    const int kbase = blockIdx.z * Kc;
    const int lrow = tid / 4;     // 0..63, + g*64
    const int lc4  = tid % 4;     // which float4 along k

    float acc[RM * 4][RN * 4] = {};
    float4 aReg[RM], bReg[RN];

    auto loadG = [&](int k0) {
#pragma unroll
        for (int g = 0; g < RM; g++) {
            int row = g * 64 + lrow;
            aReg[g] = *(const float4*)&A[(size_t)(row0 + row) * lda + k0 + lc4 * 4];
        }
#pragma unroll
        for (int g = 0; g < RN; g++) {
            int n = g * 64 + lrow;
            if (col0 + n < N)
                bReg[g] = *(const float4*)&Bm[(size_t)(col0 + n) * K + k0 + lc4 * 4];
            else
                bReg[g] = make_float4(0.f, 0.f, 0.f, 0.f);
        }
    };
    auto storeLDS = [&]() {
#pragma unroll
        for (int g = 0; g < RM; g++) {
            int row = g * 64 + lrow;
            As[(lc4 * 4 + 0) * LDA_S + row] = aReg[g].x;
            As[(lc4 * 4 + 1) * LDA_S + row] = aReg[g].y;
            As[(lc4 * 4 + 2) * LDA_S + row] = aReg[g].z;
            As[(lc4 * 4 + 3) * LDA_S + row] = aReg[g].w;
        }
#pragma unroll
        for (int g = 0; g < RN; g++) {
            int n = g * 64 + lrow;
            Bs[(lc4 * 4 + 0) * LDB_S + n] = bReg[g].x;
            Bs[(lc4 * 4 + 1) * LDB_S + n] = bReg[g].y;
            Bs[(lc4 * 4 + 2) * LDB_S + n] = bReg[g].z;
            Bs[(lc4 * 4 + 3) * LDB_S + n] = bReg[g].w;
        }
    };

    loadG(kbase);
    storeLDS();
    __syncthreads();
    for (int k0 = kbase + BK;; k0 += BK) {
        const bool has_next = (k0 < kbase + Kc);
        if (has_next) loadG(k0);      // global loads in flight during compute
#pragma unroll
        for (int k = 0; k < BK; k++) {
            float a[RM * 4], b[RN * 4];
#pragma unroll
            for (int g = 0; g < RM; g++)
                *(float4*)&a[g * 4] = *(const float4*)&As[k * LDA_S + g * 64 + tr * 4];
#pragma unroll
            for (int g = 0; g < RN; g++)
                *(float4*)&b[g * 4] = *(const float4*)&Bs[k * LDB_S + g * 64 + tc * 4];
#pragma unroll
            for (int i = 0; i < RM * 4; i++)
#pragma unroll
                for (int j = 0; j < RN * 4; j++)
                    acc[i][j] = fmaf(a[i], b[j], acc[i][j]);
        }
        if (!has_next) break;
        __syncthreads();
        storeLDS();
        __syncthreads();
    }

    float* Cout = C + (size_t)blockIdx.z * M * N;
    const bool direct = (gridDim.z == 1);
#pragma unroll
    for (int gi = 0; gi < RM; gi++)
#pragma unroll
        for (int i = 0; i < 4; i++) {
            int gm = row0 + gi * 64 + tr * 4 + i;
#pragma unroll
            for (int gj = 0; gj < RN; gj++) {
                int gn = col0 + gj * 64 + tc * 4;
                if (gn + 3 < N) {
                    float4 v;
                    v.x = acc[gi * 4 + i][gj * 4 + 0];
                    v.y = acc[gi * 4 + i][gj * 4 + 1];
                    v.z = acc[gi * 4 + i][gj * 4 + 2];
                    v.w = acc[gi * 4 + i][gj * 4 + 3];
                    if (direct && bias) {
                        float4 bv = *(const float4*)&bias[gn];
                        v.x += bv.x; v.y += bv.y; v.z += bv.z; v.w += bv.w;
                    }
                    *(float4*)&Cout[(size_t)gm * N + gn] = v;
                }
            }
        }
}

// ---------------- split-K reduce: C = sum_z parts[z] (+bias) ----------------
__global__ __launch_bounds__(256) void reduce_kernel(const float* __restrict__ parts,
                                                     float* __restrict__ C,
                                                     const float* __restrict__ bias,
                                                     long MN, int N, int SK) {
    long i = (long)blockIdx.x * 256 + threadIdx.x;      // float4 index
    if (i * 4 >= MN) return;
    float4 acc = *(const float4*)&parts[i * 4];
    for (int z = 1; z < SK; z++) {
        float4 v = *(const float4*)&parts[(size_t)z * MN + i * 4];
        acc.x += v.x; acc.y += v.y; acc.z += v.z; acc.w += v.w;
    }
    if (bias) {
        int col = (int)((i * 4) % N);
        float4 bv = *(const float4*)&bias[col];
        acc.x += bv.x; acc.y += bv.y; acc.z += bv.z; acc.w += bv.w;
    }
    *(float4*)&C[i * 4] = acc;
}

// ---------------- causal depthwise conv (DCONV=4) + SiLU ----------------
__global__ __launch_bounds__(256) void conv_silu_kernel(const float* __restrict__ xz,
                                                        const float* __restrict__ cw,
                                                        const float* __restrict__ cb,
                                                        float* __restrict__ xc) {
    size_t idx = (size_t)blockIdx.x * 256 + threadIdx.x;
    if (idx >= (size_t)RTOT * DINNER) return;
    int e = (int)(idx % DINNER);
    size_t r = idx / DINNER;
    int l = (int)(r % NP);
    size_t b = r / NP;
    const float* w = cw + (size_t)e * DCONV;
    float acc = cb[e];
#pragma unroll
    for (int k = 0; k < DCONV; k++) {
        int ls = l + k - (DCONV - 1);
        if (ls >= 0) acc += xz[(b * NP + ls) * 768 + e] * w[k];
    }
    xc[idx] = acc / (1.f + expf(-acc));   // silu
}

// ---------------- chunked selective scan: lane owns (b,d); dt-proj fused ----------------
// Pass A: local scan from h=0; record hEnd[16] and prod(dA)[16].
__global__ __launch_bounds__(128) void scanA_kernel(const float* __restrict__ xc,
                                                    const float* __restrict__ proj,
                                                    const float* __restrict__ dtw,
                                                    const float* __restrict__ dtb,
                                                    const float* __restrict__ A_log,
                                                    float* __restrict__ hEnd,
                                                    float* __restrict__ prodDA) {
    int d = blockIdx.x * 128 + threadIdx.x;       // grid.x = 3
    int c = blockIdx.y, b = blockIdx.z;
    float wreg[DTR];
    const float* w = dtw + (size_t)d * DTR;
#pragma unroll
    for (int k = 0; k < DTR; k++) wreg[k] = w[k];
    float dtbv = dtb[d];
    float a[DSTATE], h[DSTATE], p[DSTATE];
#pragma unroll
    for (int s = 0; s < DSTATE; s++) {
        a[s] = -expf(A_log[(size_t)d * DSTATE + s]);
        h[s] = 0.f;
        p[s] = 1.f;
    }
    size_t rbase = (size_t)b * NP + (size_t)c * LC;
    for (int l = 0; l < LC; l++) {
        size_t r = rbase + l;
        const float* pr = proj + r * 44;          // wave-uniform
        float pv[DTR];
        *(float4*)&pv[0] = *(const float4*)&pr[0];
        *(float4*)&pv[4] = *(const float4*)&pr[4];
        *(float4*)&pv[8] = *(const float4*)&pr[8];
        float dtv = dtbv;
#pragma unroll
        for (int k = 0; k < DTR; k++) dtv += pv[k] * wreg[k];
        dtv = (dtv > 20.f) ? dtv : log1pf(expf(dtv));   // softplus
        float du = dtv * xc[r * DINNER + d];
        float Bv[DSTATE];
        *(float4*)&Bv[0]  = *(const float4*)&pr[DTR + 0];
        *(float4*)&Bv[4]  = *(const float4*)&pr[DTR + 4];
        *(float4*)&Bv[8]  = *(const float4*)&pr[DTR + 8];
        *(float4*)&Bv[12] = *(const float4*)&pr[DTR + 12];
#pragma unroll
        for (int s = 0; s < DSTATE; s++) {
            float dA = expf(dtv * a[s]);
            h[s] = h[s] * dA + du * Bv[s];
            p[s] *= dA;
        }
    }
    float* he = hEnd   + (((size_t)b * CHUNKS + c) * DINNER + d) * DSTATE;
    float* pd = prodDA + (((size_t)b * CHUNKS + c) * DINNER + d) * DSTATE;
#pragma unroll
    for (int g = 0; g < 4; g++) {
        *(float4*)&he[g * 4] = *(float4*)&h[g * 4];
        *(float4*)&pd[g * 4] = *(float4*)&p[g * 4];
    }
}

// Pass B: sequential combine over chunks; writes hInit(c) IN PLACE over prodDA.
__global__ __launch_bounds__(256) void scanB_kernel(const float* __restrict__ hEnd,
                                                    float* __restrict__ prodDA) {
    int idx = blockIdx.x * 256 + threadIdx.x;
    if (idx >= BB * DINNER * DSTATE) return;
    int b = idx / (DINNER * DSTATE);
    int rem = idx % (DINNER * DSTATE);
    float run = 0.f;
    for (int c = 0; c < CHUNKS; c++) {
        size_t off = ((size_t)b * CHUNKS + c) * (DINNER * DSTATE) + rem;
        float p = prodDA[off];
        float e = hEnd[off];
        prodDA[off] = run;          // hInit for chunk c
        run = run * p + e;
    }
}

// Pass C: rerun local scan from hInit; y = sum_s h[s]*C[s]; fused (y+u*D)*silu(z).
// Writes y2 into xz cols [0,384); reads z from cols [384,768).
__global__ __launch_bounds__(128) void scanC_kernel(const float* __restrict__ xc,
                                                    const float* __restrict__ proj,
                                                    const float* __restrict__ dtw,
                                                    const float* __restrict__ dtb,
                                                    const float* __restrict__ hInit,
                                                    const float* __restrict__ A_log,
                                                    const float* __restrict__ Dv,
                                                    float* __restrict__ xz) {
    int d = blockIdx.x * 128 + threadIdx.x;       // grid.x = 3
    int c = blockIdx.y, b = blockIdx.z;
    float wreg[DTR];
    const float* w = dtw + (size_t)d * DTR;
#pragma unroll
    for (int k = 0; k < DTR; k++) wreg[k] = w[k];
    float dtbv = dtb[d];
    float a[DSTATE], h[DSTATE];
#pragma unroll
    for (int s = 0; s < DSTATE; s++)
        a[s] = -expf(A_log[(size_t)d * DSTATE + s]);
    const float* hi = hInit + (((size_t)b * CHUNKS + c) * DINNER + d) * DSTATE;
#pragma unroll
    for (int g = 0; g < 4; g++)
        *(float4*)&h[g * 4] = *(const float4*)&hi[g * 4];
    float Dd = Dv[d];
    size_t rbase = (size_t)b * NP + (size_t)c * LC;
    for (int l = 0; l < LC; l++) {
        size_t r = rbase + l;
        const float* pr = proj + r * 44;          // wave-uniform
        float pv[DTR];
        *(float4*)&pv[0] = *(const float4*)&pr[0];
        *(float4*)&pv[4] = *(const float4*)&pr[4];
        *(float4*)&pv[8] = *(const float4*)&pr[8];
        float dtv = dtbv;
#pragma unroll
        for (int k = 0; k < DTR; k++) dtv += pv[k] * wreg[k];
        dtv = (dtv > 20.f) ? dtv : log1pf(expf(dtv));   // softplus
        float u = xc[r * DINNER + d];
        float du = dtv * u;
        float Bv[DSTATE], Cv[DSTATE];
        *(float4*)&Bv[0]  = *(const float4*)&pr[DTR + 0];
        *(float4*)&Bv[4]  = *(const float4*)&pr[DTR + 4];
        *(float4*)&Bv[8]  = *(const float4*)&pr[DTR + 8];
        *(float4*)&Bv[12] = *(const float4*)&pr[DTR + 12];
        *(float4*)&Cv[0]  = *(const float4*)&pr[DTR + DSTATE + 0];
        *(float4*)&Cv[4]  = *(const float4*)&pr[DTR + DSTATE + 4];
        *(float4*)&Cv[8]  = *(const float4*)&pr[DTR + DSTATE + 8];
        *(float4*)&Cv[12] = *(const float4*)&pr[DTR + DSTATE + 12];
        float y = 0.f;
#pragma unroll
        for (int s = 0; s < DSTATE; s++) {
            float dA = expf(dtv * a[s]);
            h[s] = h[s] * dA + du * Bv[s];
            y = fmaf(h[s], Cv[s], y);
        }
        float z = xz[r * 768 + DINNER + d];
        xz[r * 768 + d] = (y + u * Dd) * (z / (1.f + expf(-z)));
    }
}

// ---------------- final layernorm: per-row stats ----------------
__global__ __launch_bounds__(256) void ln_stats_kernel(const float* __restrict__ x,
                                                       float* __restrict__ stats) {
    int r = blockIdx.x * 4 + (threadIdx.x >> 6);
    int lane = threadIdx.x & 63;
    if (r >= RTOT) return;
    float s = 0.f, ss = 0.f;
    for (int c = lane; c < DM; c += 64) {
        float v = x[(size_t)r * DM + c];
        s += v;
        ss += v * v;
    }
#pragma unroll
    for (int o = 32; o > 0; o >>= 1) {
        s += __shfl_down(s, o);
        ss += __shfl_down(ss, o);
    }
    if (lane == 0) {
        float mu = s / (float)DM;
        float var = ss / (float)DM - mu * mu;
        stats[r * 2] = mu;
        stats[r * 2 + 1] = rsqrtf(var + 1e-5f);
    }
}

// ---------------- normalized mean over sequence ----------------
__global__ __launch_bounds__(256) void ln_mean_kernel(const float* __restrict__ x,
                                                      const float* __restrict__ stats,
                                                      const float* __restrict__ nw,
                                                      const float* __restrict__ nb,
                                                      float* __restrict__ out) {
    int idx = blockIdx.x * 256 + threadIdx.x;
    if (idx >= BB * DM) return;
    int c = idx % DM;
    int b = idx / DM;
    float acc = 0.f;
    for (int l = 0; l < NP; l++) {
        size_t r = (size_t)b * NP + l;
        acc += (x[r * DM + c] - stats[r * 2]) * stats[r * 2 + 1];
    }
    out[idx] = acc * (1.f / (float)NP) * nw[c] + nb[c];
}

extern "C" void kernel_launch(void* const* d_in, const int* in_sizes, int n_in,
                              void* d_out, int out_size, void* d_ws, size_t ws_size,
                              hipStream_t stream) {
    const float* img     = (const float*)d_in[0];
    const float* patch_w = (const float*)d_in[1];
    const float* patch_b = (const float*)d_in[2];
    const float* in_w    = (const float*)d_in[3];
    const float* conv_w  = (const float*)d_in[4];
    const float* conv_b  = (const float*)d_in[5];
    const float* xpw     = (const float*)d_in[6];
    const float* dtw     = (const float*)d_in[7];
    const float* dtb     = (const float*)d_in[8];
    const float* A_log   = (const float*)d_in[9];
    const float* Dv      = (const float*)d_in[10];
    const float* outw    = (const float*)d_in[11];
    const float* norm_w  = (const float*)d_in[12];
    const float* norm_b  = (const float*)d_in[13];
    float* out = (float*)d_out;

    float* ws = (float*)d_ws;
    const size_t R = RTOT;
    float* xA      = ws;                   // R*192
    float* xB      = xA + R * DM;          // R*192
    float* xz      = xB + R * DM;          // R*768  (xs | z; y2 overwrites xs half)
    float* xc      = xz + R * 768;         // R*384
    float* proj    = xc + R * DINNER;      // R*44
    float* scratch = proj + R * 44;        // 9.64M floats: hEnd+prodDA OR split-K partials
    float* hEnd    = scratch;                                        // B*CHUNKS*384*16
    float* prodDA  = hEnd + (size_t)BB * CHUNKS * DINNER * DSTATE;   // same (becomes hInit)
    float* stats   = scratch + (size_t)4 * R * DM;                   // R*2 (after max partials)

    // patch embed: im2col + split-K GEMM + reduce(+bias)   M=12544, N=192, K=768, SK=4
    {
        size_t n = R * 768;
        im2col_kernel<<<dim3((unsigned)((n + 255) / 256)), 256, 0, stream>>>(img, xz);
        gemm_tile_kernel<128, 64, 2, 1><<<dim3(3, RTOT / 128, 4), 256, 0, stream>>>(
            xz, 768, patch_w, scratch, nullptr, RTOT, DM, 768, 192);
        long MN = (long)RTOT * DM;
        reduce_kernel<<<dim3((unsigned)((MN / 4 + 255) / 256)), 256, 0, stream>>>(
            scratch, xA, patch_b, MN, DM, 4);
    }

    float* xin = xA;
    float* xout = xB;
    for (int layer = 0; layer < DEPTH; layer++) {
        const float* in_w_l  = in_w + (size_t)layer * 2 * DINNER * DM;
        const float* conv_wl = conv_w + (size_t)layer * DINNER * DCONV;
        const float* conv_bl = conv_b + (size_t)layer * DINNER;
        const float* xpw_l   = xpw + (size_t)layer * (DTR + 2 * DSTATE) * DINNER;
        const float* dtw_l   = dtw + (size_t)layer * DINNER * DTR;
        const float* dtb_l   = dtb + (size_t)layer * DINNER;
        const float* Alog_l  = A_log + (size_t)layer * DINNER * DSTATE;
        const float* Dv_l    = Dv + (size_t)layer * DINNER;
        const float* outw_l  = outw + (size_t)layer * DM * DINNER;

        // xz = x @ in_w^T   (M=12544, N=768, K=192) — 1176 blocks, no split
        gemm_tile_kernel<128, 64, 2, 1><<<dim3(768 / 64, RTOT / 128, 1), 256, 0, stream>>>(
            xin, DM, in_w_l, xz, nullptr, RTOT, 2 * DINNER, DM, DM);
        // xc = silu(causal depthwise conv(xs))
        {
            size_t n = R * DINNER;
            conv_silu_kernel<<<dim3((unsigned)((n + 255) / 256)), 256, 0, stream>>>(
                xz, conv_wl, conv_bl, xc);
        }
        // proj = xc @ xpw^T   (M=12544, N=44, K=384) SK=4, Kc=96
        gemm_tile_kernel<128, 64, 2, 1><<<dim3(1, RTOT / 128, 4), 256, 0, stream>>>(
            xc, DINNER, xpw_l, scratch, nullptr, RTOT, DTR + 2 * DSTATE, DINNER, 96);
        {
            long MN = (long)RTOT * 44;
            reduce_kernel<<<dim3((unsigned)((MN / 4 + 255) / 256)), 256, 0, stream>>>(
                scratch, proj, nullptr, MN, 44, 4);
        }
        // chunked scan (dt-proj fused): A (local), B (combine), C (apply + epilogue)
        scanA_kernel<<<dim3(3, CHUNKS, BB), 128, 0, stream>>>(
            xc, proj, dtw_l, dtb_l, Alog_l, hEnd, prodDA);
        scanB_kernel<<<dim3((BB * DINNER * DSTATE + 255) / 256), 256, 0, stream>>>(
            hEnd, prodDA);
        scanC_kernel<<<dim3(3, CHUNKS, BB), 128, 0, stream>>>(
            xc, proj, dtw_l, dtb_l, prodDA, Alog_l, Dv_l, xz);
        // x_next = y2 @ outw^T   (M=12544, N=192, K=384; A = xz lda=768) SK=3, Kc=128
        gemm_tile_kernel<128, 64, 2, 1><<<dim3(DM / 64, RTOT / 128, 3), 256, 0, stream>>>(
            xz, 768, outw_l, scratch, nullptr, RTOT, DM, DINNER, 128);
        {
            long MN = (long)RTOT * DM;
            reduce_kernel<<<dim3((unsigned)((MN / 4 + 255) / 256)), 256, 0, stream>>>(
                scratch, xout, nullptr, MN, DM, 3);
        }

        float* t = xin; xin = xout; xout = t;
    }

    // final layernorm + mean over sequence
    ln_stats_kernel<<<dim3(RTOT / 4), 256, 0, stream>>>(xin, stats);
    ln_mean_kernel<<<dim3((BB * DM + 255) / 256), 256, 0, stream>>>(
        xin, stats, norm_w, norm_b, out);
}

// Round 6
// 6094.177 us; speedup vs baseline: 1.1941x; 1.1941x over previous
//
#include <hip/hip_runtime.h>
#include <hip/hip_bf16.h>
#include <math.h>

#define BB 64
#define IMG 224
#define PP 16
#define CIN 3
#define DM 192
#define DEPTH 24
#define DSTATE 16
#define DINNER 384
#define DTR 12
#define DCONV 4
#define NP 196              // (224/16)^2
#define RTOT (BB * NP)      // 12544 rows
#define CHUNKS 14
#define LC 14               // NP / CHUNKS

// ---------------- im2col for patch embed ----------------
__global__ __launch_bounds__(256) void im2col_kernel(const float* __restrict__ img,
                                                     float* __restrict__ col) {
    size_t idx = (size_t)blockIdx.x * 256 + threadIdx.x;
    if (idx >= (size_t)RTOT * 768) return;
    int t = (int)(idx % 768);
    size_t r = idx / 768;
    int l = (int)(r % NP);
    int b = (int)(r / NP);
    int ph = l / 14, pw = l % 14;
    int ci = t / 256, rem = t % 256;
    int i = rem / 16, j = rem % 16;
    col[idx] = img[(((size_t)b * CIN + ci) * IMG + ph * 16 + i) * IMG + pw * 16 + j];
}

// ---------------- tiled fp32 GEMM with optional split-K ----------------
// C[M,N] = A[M,K](lda) * B[N,K]^T. blockIdx.z = K-split slice of length Kc.
// gridDim.z == 1: write C directly (+bias). gridDim.z > 1: write partial z at
// Cout + z*M*N (bias applied by reduce kernel). M%BM==0, Kc%16==0, N%4==0.
template<int BM, int BN, int RM, int RN>
__global__ __launch_bounds__(256) void gemm_tile_kernel(const float* __restrict__ A, int lda,
                                                        const float* __restrict__ Bm,
                                                        float* __restrict__ C,
                                                        const float* __restrict__ bias,
                                                        int M, int N, int K, int Kc) {
    constexpr int BK = 16;
    constexpr int LDA_S = BM + 4;
    constexpr int LDB_S = BN + 4;
    __shared__ float As[BK * LDA_S];
    __shared__ float Bs[BK * LDB_S];
    const int tid = threadIdx.x;
    const int tr = tid / 16, tc = tid % 16;
    const int row0 = blockIdx.y * BM, col0 = blockIdx.x * BN;
    const int kbase = blockIdx.z * Kc;
    const int lrow = tid / 4;     // 0..63, + g*64
    const int lc4  = tid % 4;     // which float4 along k

    float acc[RM * 4][RN * 4] = {};
    float4 aReg[RM], bReg[RN];

    auto loadG = [&](int k0) {
#pragma unroll
        for (int g = 0; g < RM; g++) {
            int row = g * 64 + lrow;
            aReg[g] = *(const float4*)&A[(size_t)(row0 + row) * lda + k0 + lc4 * 4];
        }
#pragma unroll
        for (int g = 0; g < RN; g++) {
            int n = g * 64 + lrow;
            if (col0 + n < N)
                bReg[g] = *(const float4*)&Bm[(size_t)(col0 + n) * K + k0 + lc4 * 4];
            else
                bReg[g] = make_float4(0.f, 0.f, 0.f, 0.f);
        }
    };
    auto storeLDS = [&]() {
#pragma unroll
        for (int g = 0; g < RM; g++) {
            int row = g * 64 + lrow;
            As[(lc4 * 4 + 0) * LDA_S + row] = aReg[g].x;
            As[(lc4 * 4 + 1) * LDA_S + row] = aReg[g].y;
            As[(lc4 * 4 + 2) * LDA_S + row] = aReg[g].z;
            As[(lc4 * 4 + 3) * LDA_S + row] = aReg[g].w;
        }
#pragma unroll
        for (int g = 0; g < RN; g++) {
            int n = g * 64 + lrow;
            Bs[(lc4 * 4 + 0) * LDB_S + n] = bReg[g].x;
            Bs[(lc4 * 4 + 1) * LDB_S + n] = bReg[g].y;
            Bs[(lc4 * 4 + 2) * LDB_S + n] = bReg[g].z;
            Bs[(lc4 * 4 + 3) * LDB_S + n] = bReg[g].w;
        }
    };

    loadG(kbase);
    storeLDS();
    __syncthreads();
    for (int k0 = kbase + BK;; k0 += BK) {
        const bool has_next = (k0 < kbase + Kc);
        if (has_next) loadG(k0);      // global loads in flight during compute
#pragma unroll
        for (int k = 0; k < BK; k++) {
            float a[RM * 4], b[RN * 4];
#pragma unroll
            for (int g = 0; g < RM; g++)
                *(float4*)&a[g * 4] = *(const float4*)&As[k * LDA_S + g * 64 + tr * 4];
#pragma unroll
            for (int g = 0; g < RN; g++)
                *(float4*)&b[g * 4] = *(const float4*)&Bs[k * LDB_S + g * 64 + tc * 4];
#pragma unroll
            for (int i = 0; i < RM * 4; i++)
#pragma unroll
                for (int j = 0; j < RN * 4; j++)
                    acc[i][j] = fmaf(a[i], b[j], acc[i][j]);
        }
        if (!has_next) break;
        __syncthreads();
        storeLDS();
        __syncthreads();
    }

    float* Cout = C + (size_t)blockIdx.z * M * N;
    const bool direct = (gridDim.z == 1);
#pragma unroll
    for (int gi = 0; gi < RM; gi++)
#pragma unroll
        for (int i = 0; i < 4; i++) {
            int gm = row0 + gi * 64 + tr * 4 + i;
#pragma unroll
            for (int gj = 0; gj < RN; gj++) {
                int gn = col0 + gj * 64 + tc * 4;
                if (gn + 3 < N) {
                    float4 v;
                    v.x = acc[gi * 4 + i][gj * 4 + 0];
                    v.y = acc[gi * 4 + i][gj * 4 + 1];
                    v.z = acc[gi * 4 + i][gj * 4 + 2];
                    v.w = acc[gi * 4 + i][gj * 4 + 3];
                    if (direct && bias) {
                        float4 bv = *(const float4*)&bias[gn];
                        v.x += bv.x; v.y += bv.y; v.z += bv.z; v.w += bv.w;
                    }
                    *(float4*)&Cout[(size_t)gm * N + gn] = v;
                }
            }
        }
}

// ---------------- split-K reduce: C = sum_z parts[z] (+bias) ----------------
__global__ __launch_bounds__(256) void reduce_kernel(const float* __restrict__ parts,
                                                     float* __restrict__ C,
                                                     const float* __restrict__ bias,
                                                     long MN, int N, int SK) {
    long i = (long)blockIdx.x * 256 + threadIdx.x;      // float4 index
    if (i * 4 >= MN) return;
    float4 acc = *(const float4*)&parts[i * 4];
    for (int z = 1; z < SK; z++) {
        float4 v = *(const float4*)&parts[(size_t)z * MN + i * 4];
        acc.x += v.x; acc.y += v.y; acc.z += v.z; acc.w += v.w;
    }
    if (bias) {
        int col = (int)((i * 4) % N);
        float4 bv = *(const float4*)&bias[col];
        acc.x += bv.x; acc.y += bv.y; acc.z += bv.z; acc.w += bv.w;
    }
    *(float4*)&C[i * 4] = acc;
}

// ---------------- causal depthwise conv (DCONV=4) + SiLU ----------------
__global__ __launch_bounds__(256) void conv_silu_kernel(const float* __restrict__ xz,
                                                        const float* __restrict__ cw,
                                                        const float* __restrict__ cb,
                                                        float* __restrict__ xc) {
    size_t idx = (size_t)blockIdx.x * 256 + threadIdx.x;
    if (idx >= (size_t)RTOT * DINNER) return;
    int e = (int)(idx % DINNER);
    size_t r = idx / DINNER;
    int l = (int)(r % NP);
    size_t b = r / NP;
    const float* w = cw + (size_t)e * DCONV;
    float acc = cb[e];
#pragma unroll
    for (int k = 0; k < DCONV; k++) {
        int ls = l + k - (DCONV - 1);
        if (ls >= 0) acc += xz[(b * NP + ls) * 768 + e] * w[k];
    }
    xc[idx] = acc / (1.f + expf(-acc));   // silu
}

// ---------------- dt projection + softplus ----------------
// Writes dt into the DEAD xs-half of xz (cols [0,384), row stride 768).
// xs is dead after conv; scanC later reads dt[r,d] then overwrites the same
// slot with y2[r,d] (read-before-write within one thread).
__global__ __launch_bounds__(256) void dt_kernel(const float* __restrict__ proj,
                                                 const float* __restrict__ dtw,
                                                 const float* __restrict__ dtb,
                                                 float* __restrict__ xz) {
    int idx = blockIdx.x * 256 + threadIdx.x;
    if (idx >= RTOT * DINNER) return;
    int d = idx % DINNER;
    size_t r = (size_t)idx / DINNER;
    const float* pr = proj + r * 44;
    const float* w = dtw + (size_t)d * DTR;
    float acc = dtb[d];
#pragma unroll
    for (int k = 0; k < DTR; k++) acc += pr[k] * w[k];
    xz[r * 768 + d] = (acc > 20.f) ? acc : log1pf(expf(acc));   // softplus
}

// ---------------- chunked selective scan: lane owns (b,d), 16 states in regs ----------------
// Pass A: local scan from h=0; record hEnd[16] and prod(dA)[16].
__global__ __launch_bounds__(128) void scanA_kernel(const float* __restrict__ xc,
                                                    const float* __restrict__ proj,
                                                    const float* __restrict__ xz,
                                                    const float* __restrict__ A_log,
                                                    float* __restrict__ hEnd,
                                                    float* __restrict__ prodDA) {
    int d = blockIdx.x * 128 + threadIdx.x;       // grid.x = 3
    int c = blockIdx.y, b = blockIdx.z;
    float a[DSTATE], h[DSTATE], p[DSTATE];
#pragma unroll
    for (int s = 0; s < DSTATE; s++) {
        a[s] = -expf(A_log[(size_t)d * DSTATE + s]);
        h[s] = 0.f;
        p[s] = 1.f;
    }
    size_t rbase = (size_t)b * NP + (size_t)c * LC;
    for (int l = 0; l < LC; l++) {
        size_t r = rbase + l;
        float dtv = xz[r * 768 + d];              // dt (stored in xs-half)
        float du = dtv * xc[r * DINNER + d];
        const float* pb = proj + r * 44 + DTR;    // wave-uniform
        float Bv[DSTATE];
        *(float4*)&Bv[0]  = *(const float4*)&pb[0];
        *(float4*)&Bv[4]  = *(const float4*)&pb[4];
        *(float4*)&Bv[8]  = *(const float4*)&pb[8];
        *(float4*)&Bv[12] = *(const float4*)&pb[12];
#pragma unroll
        for (int s = 0; s < DSTATE; s++) {
            float dA = expf(dtv * a[s]);
            h[s] = h[s] * dA + du * Bv[s];
            p[s] *= dA;
        }
    }
    float* he = hEnd   + (((size_t)b * CHUNKS + c) * DINNER + d) * DSTATE;
    float* pd = prodDA + (((size_t)b * CHUNKS + c) * DINNER + d) * DSTATE;
#pragma unroll
    for (int g = 0; g < 4; g++) {
        *(float4*)&he[g * 4] = *(float4*)&h[g * 4];
        *(float4*)&pd[g * 4] = *(float4*)&p[g * 4];
    }
}

// Pass B: sequential combine over chunks; writes hInit(c) IN PLACE over prodDA.
__global__ __launch_bounds__(256) void scanB_kernel(const float* __restrict__ hEnd,
                                                    float* __restrict__ prodDA) {
    int idx = blockIdx.x * 256 + threadIdx.x;
    if (idx >= BB * DINNER * DSTATE) return;
    int b = idx / (DINNER * DSTATE);
    int rem = idx % (DINNER * DSTATE);
    float run = 0.f;
    for (int c = 0; c < CHUNKS; c++) {
        size_t off = ((size_t)b * CHUNKS + c) * (DINNER * DSTATE) + rem;
        float p = prodDA[off];
        float e = hEnd[off];
        prodDA[off] = run;          // hInit for chunk c
        run = run * p + e;
    }
}

// Pass C: rerun local scan from hInit; y = sum_s h[s]*C[s]; fused (y+u*D)*silu(z).
// Reads dt from xz cols [0,384) and z from cols [384,768); writes y2 over the
// dt slot (same thread, read-before-write per step).
__global__ __launch_bounds__(128) void scanC_kernel(const float* __restrict__ xc,
                                                    const float* __restrict__ proj,
                                                    const float* __restrict__ hInit,
                                                    const float* __restrict__ A_log,
                                                    const float* __restrict__ Dv,
                                                    float* __restrict__ xz) {
    int d = blockIdx.x * 128 + threadIdx.x;       // grid.x = 3
    int c = blockIdx.y, b = blockIdx.z;
    float a[DSTATE], h[DSTATE];
#pragma unroll
    for (int s = 0; s < DSTATE; s++)
        a[s] = -expf(A_log[(size_t)d * DSTATE + s]);
    const float* hi = hInit + (((size_t)b * CHUNKS + c) * DINNER + d) * DSTATE;
#pragma unroll
    for (int g = 0; g < 4; g++)
        *(float4*)&h[g * 4] = *(const float4*)&hi[g * 4];
    float Dd = Dv[d];
    size_t rbase = (size_t)b * NP + (size_t)c * LC;
    for (int l = 0; l < LC; l++) {
        size_t r = rbase + l;
        float dtv = xz[r * 768 + d];              // dt (stored in xs-half)
        float u = xc[r * DINNER + d];
        float du = dtv * u;
        const float* pb = proj + r * 44 + DTR;              // wave-uniform
        const float* pc = proj + r * 44 + DTR + DSTATE;
        float Bv[DSTATE], Cv[DSTATE];
        *(float4*)&Bv[0]  = *(const float4*)&pb[0];
        *(float4*)&Bv[4]  = *(const float4*)&pb[4];
        *(float4*)&Bv[8]  = *(const float4*)&pb[8];
        *(float4*)&Bv[12] = *(const float4*)&pb[12];
        *(float4*)&Cv[0]  = *(const float4*)&pc[0];
        *(float4*)&Cv[4]  = *(const float4*)&pc[4];
        *(float4*)&Cv[8]  = *(const float4*)&pc[8];
        *(float4*)&Cv[12] = *(const float4*)&pc[12];
        float y = 0.f;
#pragma unroll
        for (int s = 0; s < DSTATE; s++) {
            float dA = expf(dtv * a[s]);
            h[s] = h[s] * dA + du * Bv[s];
            y = fmaf(h[s], Cv[s], y);
        }
        float z = xz[r * 768 + DINNER + d];
        xz[r * 768 + d] = (y + u * Dd) * (z / (1.f + expf(-z)));
    }
}

// ---------------- final layernorm: per-row stats ----------------
__global__ __launch_bounds__(256) void ln_stats_kernel(const float* __restrict__ x,
                                                       float* __restrict__ stats) {
    int r = blockIdx.x * 4 + (threadIdx.x >> 6);
    int lane = threadIdx.x & 63;
    if (r >= RTOT) return;
    float s = 0.f, ss = 0.f;
    for (int c = lane; c < DM; c += 64) {
        float v = x[(size_t)r * DM + c];
        s += v;
        ss += v * v;
    }
#pragma unroll
    for (int o = 32; o > 0; o >>= 1) {
        s += __shfl_down(s, o);
        ss += __shfl_down(ss, o);
    }
    if (lane == 0) {
        float mu = s / (float)DM;
        float var = ss / (float)DM - mu * mu;
        stats[r * 2] = mu;
        stats[r * 2 + 1] = rsqrtf(var + 1e-5f);
    }
}

// ---------------- normalized mean over sequence ----------------
__global__ __launch_bounds__(256) void ln_mean_kernel(const float* __restrict__ x,
                                                      const float* __restrict__ stats,
                                                      const float* __restrict__ nw,
                                                      const float* __restrict__ nb,
                                                      float* __restrict__ out) {
    int idx = blockIdx.x * 256 + threadIdx.x;
    if (idx >= BB * DM) return;
    int c = idx % DM;
    int b = idx / DM;
    float acc = 0.f;
    for (int l = 0; l < NP; l++) {
        size_t r = (size_t)b * NP + l;
        acc += (x[r * DM + c] - stats[r * 2]) * stats[r * 2 + 1];
    }
    out[idx] = acc * (1.f / (float)NP) * nw[c] + nb[c];
}

extern "C" void kernel_launch(void* const* d_in, const int* in_sizes, int n_in,
                              void* d_out, int out_size, void* d_ws, size_t ws_size,
                              hipStream_t stream) {
    const float* img     = (const float*)d_in[0];
    const float* patch_w = (const float*)d_in[1];
    const float* patch_b = (const float*)d_in[2];
    const float* in_w    = (const float*)d_in[3];
    const float* conv_w  = (const float*)d_in[4];
    const float* conv_b  = (const float*)d_in[5];
    const float* xpw     = (const float*)d_in[6];
    const float* dtw     = (const float*)d_in[7];
    const float* dtb     = (const float*)d_in[8];
    const float* A_log   = (const float*)d_in[9];
    const float* Dv      = (const float*)d_in[10];
    const float* outw    = (const float*)d_in[11];
    const float* norm_w  = (const float*)d_in[12];
    const float* norm_b  = (const float*)d_in[13];
    float* out = (float*)d_out;

    float* ws = (float*)d_ws;
    const size_t R = RTOT;
    float* xA      = ws;                   // R*192
    float* xB      = xA + R * DM;          // R*192
    float* xz      = xB + R * DM;          // R*768  (xs | z; dt then y2 overwrite xs half)
    float* xc      = xz + R * 768;         // R*384
    float* proj    = xc + R * DINNER;      // R*44
    float* scratch = proj + R * 44;        // shared: split-K partials (<=9.64M) OR hEnd+prodDA (11.01M)
    float* hEnd    = scratch;                                        // B*CHUNKS*384*16 = 5.505M
    float* prodDA  = hEnd + (size_t)BB * CHUNKS * DINNER * DSTATE;   // same (becomes hInit)
    float* stats   = scratch + (size_t)2 * BB * CHUNKS * DINNER * DSTATE;   // R*2

    // patch embed: im2col + split-K GEMM + reduce(+bias)   M=12544, N=192, K=768, SK=4
    {
        size_t n = R * 768;
        im2col_kernel<<<dim3((unsigned)((n + 255) / 256)), 256, 0, stream>>>(img, xz);
        gemm_tile_kernel<128, 64, 2, 1><<<dim3(3, RTOT / 128, 4), 256, 0, stream>>>(
            xz, 768, patch_w, scratch, nullptr, RTOT, DM, 768, 192);
        long MN = (long)RTOT * DM;
        reduce_kernel<<<dim3((unsigned)((MN / 4 + 255) / 256)), 256, 0, stream>>>(
            scratch, xA, patch_b, MN, DM, 4);
    }

    float* xin = xA;
    float* xout = xB;
    for (int layer = 0; layer < DEPTH; layer++) {
        const float* in_w_l  = in_w + (size_t)layer * 2 * DINNER * DM;
        const float* conv_wl = conv_w + (size_t)layer * DINNER * DCONV;
        const float* conv_bl = conv_b + (size_t)layer * DINNER;
        const float* xpw_l   = xpw + (size_t)layer * (DTR + 2 * DSTATE) * DINNER;
        const float* dtw_l   = dtw + (size_t)layer * DINNER * DTR;
        const float* dtb_l   = dtb + (size_t)layer * DINNER;
        const float* Alog_l  = A_log + (size_t)layer * DINNER * DSTATE;
        const float* Dv_l    = Dv + (size_t)layer * DINNER;
        const float* outw_l  = outw + (size_t)layer * DM * DINNER;

        // xz = x @ in_w^T   (M=12544, N=768, K=192) — 1176 blocks, no split
        gemm_tile_kernel<128, 64, 2, 1><<<dim3(768 / 64, RTOT / 128, 1), 256, 0, stream>>>(
            xin, DM, in_w_l, xz, nullptr, RTOT, 2 * DINNER, DM, DM);
        // xc = silu(causal depthwise conv(xs))
        {
            size_t n = R * DINNER;
            conv_silu_kernel<<<dim3((unsigned)((n + 255) / 256)), 256, 0, stream>>>(
                xz, conv_wl, conv_bl, xc);
        }
        // proj = xc @ xpw^T   (M=12544, N=44, K=384) SK=4, Kc=96
        gemm_tile_kernel<128, 64, 2, 1><<<dim3(1, RTOT / 128, 4), 256, 0, stream>>>(
            xc, DINNER, xpw_l, scratch, nullptr, RTOT, DTR + 2 * DSTATE, DINNER, 96);
        {
            long MN = (long)RTOT * 44;
            reduce_kernel<<<dim3((unsigned)((MN / 4 + 255) / 256)), 256, 0, stream>>>(
                scratch, proj, nullptr, MN, 44, 4);
        }
        // dt = softplus(proj[:, :12] @ dtw^T + dtb) -> xz xs-half
        dt_kernel<<<dim3((RTOT * DINNER + 255) / 256), 256, 0, stream>>>(
            proj, dtw_l, dtb_l, xz);
        // chunked scan: A (local), B (combine), C (apply + epilogue -> xz xs-half)
        scanA_kernel<<<dim3(3, CHUNKS, BB), 128, 0, stream>>>(
            xc, proj, xz, Alog_l, hEnd, prodDA);
        scanB_kernel<<<dim3((BB * DINNER * DSTATE + 255) / 256), 256, 0, stream>>>(
            hEnd, prodDA);
        scanC_kernel<<<dim3(3, CHUNKS, BB), 128, 0, stream>>>(
            xc, proj, prodDA, Alog_l, Dv_l, xz);
        // x_next = y2 @ outw^T   (M=12544, N=192, K=384; A = xz lda=768) SK=3, Kc=128
        gemm_tile_kernel<128, 64, 2, 1><<<dim3(DM / 64, RTOT / 128, 3), 256, 0, stream>>>(
            xz, 768, outw_l, scratch, nullptr, RTOT, DM, DINNER, 128);
        {
            long MN = (long)RTOT * DM;
            reduce_kernel<<<dim3((unsigned)((MN / 4 + 255) / 256)), 256, 0, stream>>>(
                scratch, xout, nullptr, MN, DM, 3);
        }

        float* t = xin; xin = xout; xout = t;
    }

    // final layernorm + mean over sequence
    ln_stats_kernel<<<dim3(RTOT / 4), 256, 0, stream>>>(xin, stats);
    ln_mean_kernel<<<dim3((BB * DM + 255) / 256), 256, 0, stream>>>(
        xin, stats, norm_w, norm_b, out);
}

// Round 7
// 5375.260 us; speedup vs baseline: 1.3538x; 1.1337x over previous
//
#include <hip/hip_runtime.h>
#include <hip/hip_bf16.h>
#include <math.h>

#define BB 64
#define IMG 224
#define PP 16
#define CIN 3
#define DM 192
#define DEPTH 24
#define DSTATE 16
#define DINNER 384
#define DTR 12
#define DCONV 4
#define NP 196              // (224/16)^2
#define RTOT (BB * NP)      // 12544 rows
#define CHUNKS 14
#define LC 14               // NP / CHUNKS

typedef short bf16x8 __attribute__((ext_vector_type(8)));
typedef float f32x4 __attribute__((ext_vector_type(4)));

__device__ inline unsigned short f2bf_rne(float f) {
    unsigned u = __float_as_uint(f);
    unsigned r = u + 0x7fffu + ((u >> 16) & 1u);
    return (unsigned short)(r >> 16);
}
__device__ inline float bf2f(unsigned short s) {
    return __uint_as_float(((unsigned)s) << 16);
}

// ---------------- im2col for patch embed ----------------
__global__ __launch_bounds__(256) void im2col_kernel(const float* __restrict__ img,
                                                     float* __restrict__ col) {
    size_t idx = (size_t)blockIdx.x * 256 + threadIdx.x;
    if (idx >= (size_t)RTOT * 768) return;
    int t = (int)(idx % 768);
    size_t r = idx / 768;
    int l = (int)(r % NP);
    int b = (int)(r / NP);
    int ph = l / 14, pw = l % 14;
    int ci = t / 256, rem = t % 256;
    int i = rem / 16, j = rem % 16;
    col[idx] = img[(((size_t)b * CIN + ci) * IMG + ph * 16 + i) * IMG + pw * 16 + j];
}

// ---------------- bf16 hi/lo MFMA GEMM: C[M,N] = A[M,K](lda) * B[N,K]^T ----------------
// fp32 inputs split in-register to hi+lo bf16; D += Ah*Bh + Ah*Bl + Al*Bh (fp32 acc).
// BM=128, BK=32, 256 threads = 4 waves (2x2), wave tile 64 x BN/2, 16x16x32 MFMA.
// blockIdx.z = split-K slice (length Kc). gridDim.z==1: direct write (+bias);
// else partial z written at C + z*M*N (bias applied by reduce_kernel).
// Requirements: M%128==0, Kc%32==0.
template<int BN>
__global__ __launch_bounds__(256) void gemm_mfma_kernel(const float* __restrict__ A, int lda,
                                                        const float* __restrict__ Bm,
                                                        float* __restrict__ C,
                                                        const float* __restrict__ bias,
                                                        int M, int N, int K, int Kc) {
    constexpr int BM = 128, BK = 32;
    constexpr int LDS = BK + 8;                 // 40 shorts = 80 B row stride
    constexpr int NF = BN / 32;                 // n-frags per wave
    constexpr int BSTG = BN / 32;               // B rows staged per thread
    __shared__ short AsH[BM * LDS], AsL[BM * LDS];
    __shared__ short BsH[BN * LDS], BsL[BN * LDS];

    const int tid = threadIdx.x;
    const int lane = tid & 63;
    const int wid = tid >> 6;
    const int wr = wid >> 1, wc = wid & 1;      // 2x2 wave grid
    const int row0 = blockIdx.y * BM, col0 = blockIdx.x * BN;
    const int kbase = blockIdx.z * Kc;
    const int sr = tid >> 3;                    // staging row (0..31)
    const int sc = (tid & 7) * 4;               // staging col in floats/shorts

    float aRf[4][4];
    float bRf[BSTG][4];
    f32x4 acc[4][NF] = {};

    auto loadG = [&](int k0) {
#pragma unroll
        for (int i = 0; i < 4; i++)
            *(float4*)aRf[i] = *(const float4*)&A[(size_t)(row0 + sr + 32 * i) * lda + k0 + sc];
#pragma unroll
        for (int i = 0; i < BSTG; i++) {
            int n = sr + 32 * i;
            if (col0 + n < N)
                *(float4*)bRf[i] = *(const float4*)&Bm[(size_t)(col0 + n) * K + k0 + sc];
            else {
                bRf[i][0] = 0.f; bRf[i][1] = 0.f; bRf[i][2] = 0.f; bRf[i][3] = 0.f;
            }
        }
    };
    auto storeLDS = [&]() {
#pragma unroll
        for (int i = 0; i < 4; i++) {
            int row = sr + 32 * i;
            short4 h, l;
            unsigned short hs;
            hs = f2bf_rne(aRf[i][0]); h.x = (short)hs; l.x = (short)f2bf_rne(aRf[i][0] - bf2f(hs));
            hs = f2bf_rne(aRf[i][1]); h.y = (short)hs; l.y = (short)f2bf_rne(aRf[i][1] - bf2f(hs));
            hs = f2bf_rne(aRf[i][2]); h.z = (short)hs; l.z = (short)f2bf_rne(aRf[i][2] - bf2f(hs));
            hs = f2bf_rne(aRf[i][3]); h.w = (short)hs; l.w = (short)f2bf_rne(aRf[i][3] - bf2f(hs));
            *(short4*)&AsH[row * LDS + sc] = h;
            *(short4*)&AsL[row * LDS + sc] = l;
        }
#pragma unroll
        for (int i = 0; i < BSTG; i++) {
            int row = sr + 32 * i;
            short4 h, l;
            unsigned short hs;
            hs = f2bf_rne(bRf[i][0]); h.x = (short)hs; l.x = (short)f2bf_rne(bRf[i][0] - bf2f(hs));
            hs = f2bf_rne(bRf[i][1]); h.y = (short)hs; l.y = (short)f2bf_rne(bRf[i][1] - bf2f(hs));
            hs = f2bf_rne(bRf[i][2]); h.z = (short)hs; l.z = (short)f2bf_rne(bRf[i][2] - bf2f(hs));
            hs = f2bf_rne(bRf[i][3]); h.w = (short)hs; l.w = (short)f2bf_rne(bRf[i][3] - bf2f(hs));
            *(short4*)&BsH[row * LDS + sc] = h;
            *(short4*)&BsL[row * LDS + sc] = l;
        }
    };

    loadG(kbase);
    storeLDS();
    __syncthreads();
    for (int k0 = kbase + BK;; k0 += BK) {
        const bool has_next = (k0 < kbase + Kc);
        if (has_next) loadG(k0);
        // fragment loads + MFMA
        {
            const int fr = lane & 15;           // row/col within 16-frag
            const int kg = (lane >> 4) * 8;     // k offset within BK=32
            bf16x8 aH[4], aL[4], bH[NF], bL[NF];
#pragma unroll
            for (int i = 0; i < 4; i++) {
                int row = wr * 64 + i * 16 + fr;
                aH[i] = *(const bf16x8*)&AsH[row * LDS + kg];
                aL[i] = *(const bf16x8*)&AsL[row * LDS + kg];
            }
#pragma unroll
            for (int j = 0; j < NF; j++) {
                int row = wc * (BN / 2) + j * 16 + fr;
                bH[j] = *(const bf16x8*)&BsH[row * LDS + kg];
                bL[j] = *(const bf16x8*)&BsL[row * LDS + kg];
            }
#pragma unroll
            for (int i = 0; i < 4; i++)
#pragma unroll
                for (int j = 0; j < NF; j++) {
                    acc[i][j] = __builtin_amdgcn_mfma_f32_16x16x32_bf16(aH[i], bH[j], acc[i][j], 0, 0, 0);
                    acc[i][j] = __builtin_amdgcn_mfma_f32_16x16x32_bf16(aH[i], bL[j], acc[i][j], 0, 0, 0);
                    acc[i][j] = __builtin_amdgcn_mfma_f32_16x16x32_bf16(aL[i], bH[j], acc[i][j], 0, 0, 0);
                }
        }
        if (!has_next) break;
        __syncthreads();
        storeLDS();
        __syncthreads();
    }

    float* Cout = C + (size_t)blockIdx.z * M * N;
    const bool direct = (gridDim.z == 1);
    const int crow = (lane >> 4) * 4;
    const int ccol = lane & 15;
#pragma unroll
    for (int i = 0; i < 4; i++) {
#pragma unroll
        for (int j = 0; j < NF; j++) {
            int gn = col0 + wc * (BN / 2) + j * 16 + ccol;
            if (gn >= N) continue;
            int gm0 = row0 + wr * 64 + i * 16 + crow;
            float bv = (direct && bias) ? bias[gn] : 0.f;
#pragma unroll
            for (int reg = 0; reg < 4; reg++)
                Cout[(size_t)(gm0 + reg) * N + gn] = acc[i][j][reg] + bv;
        }
    }
}

// ---------------- split-K reduce: C = sum_z parts[z] (+bias) ----------------
__global__ __launch_bounds__(256) void reduce_kernel(const float* __restrict__ parts,
                                                     float* __restrict__ C,
                                                     const float* __restrict__ bias,
                                                     long MN, int N, int SK) {
    long i = (long)blockIdx.x * 256 + threadIdx.x;      // float4 index
    if (i * 4 >= MN) return;
    float4 acc = *(const float4*)&parts[i * 4];
    for (int z = 1; z < SK; z++) {
        float4 v = *(const float4*)&parts[(size_t)z * MN + i * 4];
        acc.x += v.x; acc.y += v.y; acc.z += v.z; acc.w += v.w;
    }
    if (bias) {
        int col = (int)((i * 4) % N);
        float4 bv = *(const float4*)&bias[col];
        acc.x += bv.x; acc.y += bv.y; acc.z += bv.z; acc.w += bv.w;
    }
    *(float4*)&C[i * 4] = acc;
}

// ---------------- causal depthwise conv (DCONV=4) + SiLU ----------------
__global__ __launch_bounds__(256) void conv_silu_kernel(const float* __restrict__ xz,
                                                        const float* __restrict__ cw,
                                                        const float* __restrict__ cb,
                                                        float* __restrict__ xc) {
    size_t idx = (size_t)blockIdx.x * 256 + threadIdx.x;
    if (idx >= (size_t)RTOT * DINNER) return;
    int e = (int)(idx % DINNER);
    size_t r = idx / DINNER;
    int l = (int)(r % NP);
    size_t b = r / NP;
    const float* w = cw + (size_t)e * DCONV;
    float acc = cb[e];
#pragma unroll
    for (int k = 0; k < DCONV; k++) {
        int ls = l + k - (DCONV - 1);
        if (ls >= 0) acc += xz[(b * NP + ls) * 768 + e] * w[k];
    }
    xc[idx] = acc / (1.f + expf(-acc));   // silu
}

// ---------------- dt projection + softplus ----------------
// Writes dt into the DEAD xs-half of xz (cols [0,384), row stride 768).
__global__ __launch_bounds__(256) void dt_kernel(const float* __restrict__ proj,
                                                 const float* __restrict__ dtw,
                                                 const float* __restrict__ dtb,
                                                 float* __restrict__ xz) {
    int idx = blockIdx.x * 256 + threadIdx.x;
    if (idx >= RTOT * DINNER) return;
    int d = idx % DINNER;
    size_t r = (size_t)idx / DINNER;
    const float* pr = proj + r * 44;
    const float* w = dtw + (size_t)d * DTR;
    float acc = dtb[d];
#pragma unroll
    for (int k = 0; k < DTR; k++) acc += pr[k] * w[k];
    xz[r * 768 + d] = (acc > 20.f) ? acc : log1pf(expf(acc));   // softplus
}

// ---------------- chunked selective scan: lane owns (b,d), 16 states in regs ----------------
__global__ __launch_bounds__(128) void scanA_kernel(const float* __restrict__ xc,
                                                    const float* __restrict__ proj,
                                                    const float* __restrict__ xz,
                                                    const float* __restrict__ A_log,
                                                    float* __restrict__ hEnd,
                                                    float* __restrict__ prodDA) {
    int d = blockIdx.x * 128 + threadIdx.x;       // grid.x = 3
    int c = blockIdx.y, b = blockIdx.z;
    float a[DSTATE], h[DSTATE], p[DSTATE];
#pragma unroll
    for (int s = 0; s < DSTATE; s++) {
        a[s] = -expf(A_log[(size_t)d * DSTATE + s]);
        h[s] = 0.f;
        p[s] = 1.f;
    }
    size_t rbase = (size_t)b * NP + (size_t)c * LC;
    for (int l = 0; l < LC; l++) {
        size_t r = rbase + l;
        float dtv = xz[r * 768 + d];              // dt (stored in xs-half)
        float du = dtv * xc[r * DINNER + d];
        const float* pb = proj + r * 44 + DTR;    // wave-uniform
        float Bv[DSTATE];
        *(float4*)&Bv[0]  = *(const float4*)&pb[0];
        *(float4*)&Bv[4]  = *(const float4*)&pb[4];
        *(float4*)&Bv[8]  = *(const float4*)&pb[8];
        *(float4*)&Bv[12] = *(const float4*)&pb[12];
#pragma unroll
        for (int s = 0; s < DSTATE; s++) {
            float dA = expf(dtv * a[s]);
            h[s] = h[s] * dA + du * Bv[s];
            p[s] *= dA;
        }
    }
    float* he = hEnd   + (((size_t)b * CHUNKS + c) * DINNER + d) * DSTATE;
    float* pd = prodDA + (((size_t)b * CHUNKS + c) * DINNER + d) * DSTATE;
#pragma unroll
    for (int g = 0; g < 4; g++) {
        *(float4*)&he[g * 4] = *(float4*)&h[g * 4];
        *(float4*)&pd[g * 4] = *(float4*)&p[g * 4];
    }
}

__global__ __launch_bounds__(256) void scanB_kernel(const float* __restrict__ hEnd,
                                                    float* __restrict__ prodDA) {
    int idx = blockIdx.x * 256 + threadIdx.x;
    if (idx >= BB * DINNER * DSTATE) return;
    int b = idx / (DINNER * DSTATE);
    int rem = idx % (DINNER * DSTATE);
    float run = 0.f;
    for (int c = 0; c < CHUNKS; c++) {
        size_t off = ((size_t)b * CHUNKS + c) * (DINNER * DSTATE) + rem;
        float p = prodDA[off];
        float e = hEnd[off];
        prodDA[off] = run;          // hInit for chunk c
        run = run * p + e;
    }
}

__global__ __launch_bounds__(128) void scanC_kernel(const float* __restrict__ xc,
                                                    const float* __restrict__ proj,
                                                    const float* __restrict__ hInit,
                                                    const float* __restrict__ A_log,
                                                    const float* __restrict__ Dv,
                                                    float* __restrict__ xz) {
    int d = blockIdx.x * 128 + threadIdx.x;       // grid.x = 3
    int c = blockIdx.y, b = blockIdx.z;
    float a[DSTATE], h[DSTATE];
#pragma unroll
    for (int s = 0; s < DSTATE; s++)
        a[s] = -expf(A_log[(size_t)d * DSTATE + s]);
    const float* hi = hInit + (((size_t)b * CHUNKS + c) * DINNER + d) * DSTATE;
#pragma unroll
    for (int g = 0; g < 4; g++)
        *(float4*)&h[g * 4] = *(const float4*)&hi[g * 4];
    float Dd = Dv[d];
    size_t rbase = (size_t)b * NP + (size_t)c * LC;
    for (int l = 0; l < LC; l++) {
        size_t r = rbase + l;
        float dtv = xz[r * 768 + d];              // dt (stored in xs-half)
        float u = xc[r * DINNER + d];
        float du = dtv * u;
        const float* pb = proj + r * 44 + DTR;              // wave-uniform
        const float* pc = proj + r * 44 + DTR + DSTATE;
        float Bv[DSTATE], Cv[DSTATE];
        *(float4*)&Bv[0]  = *(const float4*)&pb[0];
        *(float4*)&Bv[4]  = *(const float4*)&pb[4];
        *(float4*)&Bv[8]  = *(const float4*)&pb[8];
        *(float4*)&Bv[12] = *(const float4*)&pb[12];
        *(float4*)&Cv[0]  = *(const float4*)&pc[0];
        *(float4*)&Cv[4]  = *(const float4*)&pc[4];
        *(float4*)&Cv[8]  = *(const float4*)&pc[8];
        *(float4*)&Cv[12] = *(const float4*)&pc[12];
        float y = 0.f;
#pragma unroll
        for (int s = 0; s < DSTATE; s++) {
            float dA = expf(dtv * a[s]);
            h[s] = h[s] * dA + du * Bv[s];
            y = fmaf(h[s], Cv[s], y);
        }
        float z = xz[r * 768 + DINNER + d];
        xz[r * 768 + d] = (y + u * Dd) * (z / (1.f + expf(-z)));
    }
}

// ---------------- final layernorm: per-row stats ----------------
__global__ __launch_bounds__(256) void ln_stats_kernel(const float* __restrict__ x,
                                                       float* __restrict__ stats) {
    int r = blockIdx.x * 4 + (threadIdx.x >> 6);
    int lane = threadIdx.x & 63;
    if (r >= RTOT) return;
    float s = 0.f, ss = 0.f;
    for (int c = lane; c < DM; c += 64) {
        float v = x[(size_t)r * DM + c];
        s += v;
        ss += v * v;
    }
#pragma unroll
    for (int o = 32; o > 0; o >>= 1) {
        s += __shfl_down(s, o);
        ss += __shfl_down(ss, o);
    }
    if (lane == 0) {
        float mu = s / (float)DM;
        float var = ss / (float)DM - mu * mu;
        stats[r * 2] = mu;
        stats[r * 2 + 1] = rsqrtf(var + 1e-5f);
    }
}

// ---------------- normalized mean over sequence ----------------
__global__ __launch_bounds__(256) void ln_mean_kernel(const float* __restrict__ x,
                                                      const float* __restrict__ stats,
                                                      const float* __restrict__ nw,
                                                      const float* __restrict__ nb,
                                                      float* __restrict__ out) {
    int idx = blockIdx.x * 256 + threadIdx.x;
    if (idx >= BB * DM) return;
    int c = idx % DM;
    int b = idx / DM;
    float acc = 0.f;
    for (int l = 0; l < NP; l++) {
        size_t r = (size_t)b * NP + l;
        acc += (x[r * DM + c] - stats[r * 2]) * stats[r * 2 + 1];
    }
    out[idx] = acc * (1.f / (float)NP) * nw[c] + nb[c];
}

extern "C" void kernel_launch(void* const* d_in, const int* in_sizes, int n_in,
                              void* d_out, int out_size, void* d_ws, size_t ws_size,
                              hipStream_t stream) {
    const float* img     = (const float*)d_in[0];
    const float* patch_w = (const float*)d_in[1];
    const float* patch_b = (const float*)d_in[2];
    const float* in_w    = (const float*)d_in[3];
    const float* conv_w  = (const float*)d_in[4];
    const float* conv_b  = (const float*)d_in[5];
    const float* xpw     = (const float*)d_in[6];
    const float* dtw     = (const float*)d_in[7];
    const float* dtb     = (const float*)d_in[8];
    const float* A_log   = (const float*)d_in[9];
    const float* Dv      = (const float*)d_in[10];
    const float* outw    = (const float*)d_in[11];
    const float* norm_w  = (const float*)d_in[12];
    const float* norm_b  = (const float*)d_in[13];
    float* out = (float*)d_out;

    float* ws = (float*)d_ws;
    const size_t R = RTOT;
    float* xA      = ws;                   // R*192
    float* xB      = xA + R * DM;          // R*192
    float* xz      = xB + R * DM;          // R*768  (xs | z; dt then y2 overwrite xs half)
    float* xc      = xz + R * 768;         // R*384
    float* proj    = xc + R * DINNER;      // R*44
    float* scratch = proj + R * 44;        // shared: split-K partials (<=9.64M) OR hEnd+prodDA (11.01M)
    float* hEnd    = scratch;                                        // B*CHUNKS*384*16 = 5.505M
    float* prodDA  = hEnd + (size_t)BB * CHUNKS * DINNER * DSTATE;   // same (becomes hInit)
    float* stats   = scratch + (size_t)2 * BB * CHUNKS * DINNER * DSTATE;   // R*2

    // patch embed: im2col + split-K MFMA GEMM + reduce(+bias)  M=12544, N=192, K=768, SK=4
    {
        size_t n = R * 768;
        im2col_kernel<<<dim3((unsigned)((n + 255) / 256)), 256, 0, stream>>>(img, xz);
        gemm_mfma_kernel<64><<<dim3(3, RTOT / 128, 4), 256, 0, stream>>>(
            xz, 768, patch_w, scratch, nullptr, RTOT, DM, 768, 192);
        long MN = (long)RTOT * DM;
        reduce_kernel<<<dim3((unsigned)((MN / 4 + 255) / 256)), 256, 0, stream>>>(
            scratch, xA, patch_b, MN, DM, 4);
    }

    float* xin = xA;
    float* xout = xB;
    for (int layer = 0; layer < DEPTH; layer++) {
        const float* in_w_l  = in_w + (size_t)layer * 2 * DINNER * DM;
        const float* conv_wl = conv_w + (size_t)layer * DINNER * DCONV;
        const float* conv_bl = conv_b + (size_t)layer * DINNER;
        const float* xpw_l   = xpw + (size_t)layer * (DTR + 2 * DSTATE) * DINNER;
        const float* dtw_l   = dtw + (size_t)layer * DINNER * DTR;
        const float* dtb_l   = dtb + (size_t)layer * DINNER;
        const float* Alog_l  = A_log + (size_t)layer * DINNER * DSTATE;
        const float* Dv_l    = Dv + (size_t)layer * DINNER;
        const float* outw_l  = outw + (size_t)layer * DM * DINNER;

        // xz = x @ in_w^T   (M=12544, N=768, K=192) — direct, 588 blocks
        gemm_mfma_kernel<128><<<dim3(768 / 128, RTOT / 128, 1), 256, 0, stream>>>(
            xin, DM, in_w_l, xz, nullptr, RTOT, 2 * DINNER, DM, DM);
        // xc = silu(causal depthwise conv(xs))
        {
            size_t n = R * DINNER;
            conv_silu_kernel<<<dim3((unsigned)((n + 255) / 256)), 256, 0, stream>>>(
                xz, conv_wl, conv_bl, xc);
        }
        // proj = xc @ xpw^T   (M=12544, N=44, K=384) SK=4, Kc=96
        gemm_mfma_kernel<64><<<dim3(1, RTOT / 128, 4), 256, 0, stream>>>(
            xc, DINNER, xpw_l, scratch, nullptr, RTOT, DTR + 2 * DSTATE, DINNER, 96);
        {
            long MN = (long)RTOT * 44;
            reduce_kernel<<<dim3((unsigned)((MN / 4 + 255) / 256)), 256, 0, stream>>>(
                scratch, proj, nullptr, MN, 44, 4);
        }
        // dt = softplus(proj[:, :12] @ dtw^T + dtb) -> xz xs-half
        dt_kernel<<<dim3((RTOT * DINNER + 255) / 256), 256, 0, stream>>>(
            proj, dtw_l, dtb_l, xz);
        // chunked scan: A (local), B (combine), C (apply + epilogue -> xz xs-half)
        scanA_kernel<<<dim3(3, CHUNKS, BB), 128, 0, stream>>>(
            xc, proj, xz, Alog_l, hEnd, prodDA);
        scanB_kernel<<<dim3((BB * DINNER * DSTATE + 255) / 256), 256, 0, stream>>>(
            hEnd, prodDA);
        scanC_kernel<<<dim3(3, CHUNKS, BB), 128, 0, stream>>>(
            xc, proj, prodDA, Alog_l, Dv_l, xz);
        // x_next = y2 @ outw^T   (M=12544, N=192, K=384; A = xz lda=768) SK=3, Kc=128
        gemm_mfma_kernel<64><<<dim3(DM / 64, RTOT / 128, 3), 256, 0, stream>>>(
            xz, 768, outw_l, scratch, nullptr, RTOT, DM, DINNER, 128);
        {
            long MN = (long)RTOT * DM;
            reduce_kernel<<<dim3((unsigned)((MN / 4 + 255) / 256)), 256, 0, stream>>>(
                scratch, xout, nullptr, MN, DM, 3);
        }

        float* t = xin; xin = xout; xout = t;
    }

    // final layernorm + mean over sequence
    ln_stats_kernel<<<dim3(RTOT / 4), 256, 0, stream>>>(xin, stats);
    ln_mean_kernel<<<dim3((BB * DM + 255) / 256), 256, 0, stream>>>(
        xin, stats, norm_w, norm_b, out);
}

// Round 8
// 4242.239 us; speedup vs baseline: 1.7154x; 1.2671x over previous
//
#include <hip/hip_runtime.h>
#include <hip/hip_bf16.h>
#include <math.h>

#define BB 64
#define IMG 224
#define PP 16
#define CIN 3
#define DM 192
#define DEPTH 24
#define DSTATE 16
#define DINNER 384
#define DTR 12
#define DCONV 4
#define NP 196              // (224/16)^2
#define RTOT (BB * NP)      // 12544 rows
#define CHUNKS 14
#define LC 14               // NP / CHUNKS

typedef short bf16x8 __attribute__((ext_vector_type(8)));
typedef float f32x4 __attribute__((ext_vector_type(4)));

__device__ inline unsigned short f2bf_rne(float f) {
    unsigned u = __float_as_uint(f);
    unsigned r = u + 0x7fffu + ((u >> 16) & 1u);
    return (unsigned short)(r >> 16);
}
__device__ inline float bf2f(unsigned short s) {
    return __uint_as_float(((unsigned)s) << 16);
}

// ---------------- im2col for patch embed ----------------
__global__ __launch_bounds__(256) void im2col_kernel(const float* __restrict__ img,
                                                     float* __restrict__ col) {
    size_t idx = (size_t)blockIdx.x * 256 + threadIdx.x;
    if (idx >= (size_t)RTOT * 768) return;
    int t = (int)(idx % 768);
    size_t r = idx / 768;
    int l = (int)(r % NP);
    int b = (int)(r / NP);
    int ph = l / 14, pw = l % 14;
    int ci = t / 256, rem = t % 256;
    int i = rem / 16, j = rem % 16;
    col[idx] = img[(((size_t)b * CIN + ci) * IMG + ph * 16 + i) * IMG + pw * 16 + j];
}

// ---------------- bf16 hi/lo MFMA GEMM: C[M,N] = A[M,K](lda) * B[N,K]^T ----------------
// fp32 inputs split in-register to hi+lo bf16; D += Ah*Bh + Ah*Bl + Al*Bh (fp32 acc).
// BM=128, BK=32, 256 threads = 4 waves (2x2), wave tile 64 x BN/2, 16x16x32 MFMA.
// blockIdx.z = split-K slice (length Kc). gridDim.z==1: direct write (+bias);
// else partial z written at C + z*M*N (bias applied by reduce_kernel).
// Requirements: M%128==0, Kc%32==0.
template<int BN>
__global__ __launch_bounds__(256) void gemm_mfma_kernel(const float* __restrict__ A, int lda,
                                                        const float* __restrict__ Bm,
                                                        float* __restrict__ C,
                                                        const float* __restrict__ bias,
                                                        int M, int N, int K, int Kc) {
    constexpr int BM = 128, BK = 32;
    constexpr int LDS = BK + 8;                 // 40 shorts = 80 B row stride
    constexpr int NF = BN / 32;                 // n-frags per wave
    constexpr int BSTG = BN / 32;               // B rows staged per thread
    __shared__ short AsH[BM * LDS], AsL[BM * LDS];
    __shared__ short BsH[BN * LDS], BsL[BN * LDS];

    const int tid = threadIdx.x;
    const int lane = tid & 63;
    const int wid = tid >> 6;
    const int wr = wid >> 1, wc = wid & 1;      // 2x2 wave grid
    const int row0 = blockIdx.y * BM, col0 = blockIdx.x * BN;
    const int kbase = blockIdx.z * Kc;
    const int sr = tid >> 3;                    // staging row (0..31)
    const int sc = (tid & 7) * 4;               // staging col in floats/shorts

    float aRf[4][4];
    float bRf[BSTG][4];
    f32x4 acc[4][NF] = {};

    auto loadG = [&](int k0) {
#pragma unroll
        for (int i = 0; i < 4; i++)
            *(float4*)aRf[i] = *(const float4*)&A[(size_t)(row0 + sr + 32 * i) * lda + k0 + sc];
#pragma unroll
        for (int i = 0; i < BSTG; i++) {
            int n = sr + 32 * i;
            if (col0 + n < N)
                *(float4*)bRf[i] = *(const float4*)&Bm[(size_t)(col0 + n) * K + k0 + sc];
            else {
                bRf[i][0] = 0.f; bRf[i][1] = 0.f; bRf[i][2] = 0.f; bRf[i][3] = 0.f;
            }
        }
    };
    auto storeLDS = [&]() {
#pragma unroll
        for (int i = 0; i < 4; i++) {
            int row = sr + 32 * i;
            short4 h, l;
            unsigned short hs;
            hs = f2bf_rne(aRf[i][0]); h.x = (short)hs; l.x = (short)f2bf_rne(aRf[i][0] - bf2f(hs));
            hs = f2bf_rne(aRf[i][1]); h.y = (short)hs; l.y = (short)f2bf_rne(aRf[i][1] - bf2f(hs));
            hs = f2bf_rne(aRf[i][2]); h.z = (short)hs; l.z = (short)f2bf_rne(aRf[i][2] - bf2f(hs));
            hs = f2bf_rne(aRf[i][3]); h.w = (short)hs; l.w = (short)f2bf_rne(aRf[i][3] - bf2f(hs));
            *(short4*)&AsH[row * LDS + sc] = h;
            *(short4*)&AsL[row * LDS + sc] = l;
        }
#pragma unroll
        for (int i = 0; i < BSTG; i++) {
            int row = sr + 32 * i;
            short4 h, l;
            unsigned short hs;
            hs = f2bf_rne(bRf[i][0]); h.x = (short)hs; l.x = (short)f2bf_rne(bRf[i][0] - bf2f(hs));
            hs = f2bf_rne(bRf[i][1]); h.y = (short)hs; l.y = (short)f2bf_rne(bRf[i][1] - bf2f(hs));
            hs = f2bf_rne(bRf[i][2]); h.z = (short)hs; l.z = (short)f2bf_rne(bRf[i][2] - bf2f(hs));
            hs = f2bf_rne(bRf[i][3]); h.w = (short)hs; l.w = (short)f2bf_rne(bRf[i][3] - bf2f(hs));
            *(short4*)&BsH[row * LDS + sc] = h;
            *(short4*)&BsL[row * LDS + sc] = l;
        }
    };

    loadG(kbase);
    storeLDS();
    __syncthreads();
    for (int k0 = kbase + BK;; k0 += BK) {
        const bool has_next = (k0 < kbase + Kc);
        if (has_next) loadG(k0);
        // fragment loads + MFMA
        {
            const int fr = lane & 15;           // row/col within 16-frag
            const int kg = (lane >> 4) * 8;     // k offset within BK=32
            bf16x8 aH[4], aL[4], bH[NF], bL[NF];
#pragma unroll
            for (int i = 0; i < 4; i++) {
                int row = wr * 64 + i * 16 + fr;
                aH[i] = *(const bf16x8*)&AsH[row * LDS + kg];
                aL[i] = *(const bf16x8*)&AsL[row * LDS + kg];
            }
#pragma unroll
            for (int j = 0; j < NF; j++) {
                int row = wc * (BN / 2) + j * 16 + fr;
                bH[j] = *(const bf16x8*)&BsH[row * LDS + kg];
                bL[j] = *(const bf16x8*)&BsL[row * LDS + kg];
            }
#pragma unroll
            for (int i = 0; i < 4; i++)
#pragma unroll
                for (int j = 0; j < NF; j++) {
                    acc[i][j] = __builtin_amdgcn_mfma_f32_16x16x32_bf16(aH[i], bH[j], acc[i][j], 0, 0, 0);
                    acc[i][j] = __builtin_amdgcn_mfma_f32_16x16x32_bf16(aH[i], bL[j], acc[i][j], 0, 0, 0);
                    acc[i][j] = __builtin_amdgcn_mfma_f32_16x16x32_bf16(aL[i], bH[j], acc[i][j], 0, 0, 0);
                }
        }
        if (!has_next) break;
        __syncthreads();
        storeLDS();
        __syncthreads();
    }

    float* Cout = C + (size_t)blockIdx.z * M * N;
    const bool direct = (gridDim.z == 1);
    const int crow = (lane >> 4) * 4;
    const int ccol = lane & 15;
#pragma unroll
    for (int i = 0; i < 4; i++) {
#pragma unroll
        for (int j = 0; j < NF; j++) {
            int gn = col0 + wc * (BN / 2) + j * 16 + ccol;
            if (gn >= N) continue;
            int gm0 = row0 + wr * 64 + i * 16 + crow;
            float bv = (direct && bias) ? bias[gn] : 0.f;
#pragma unroll
            for (int reg = 0; reg < 4; reg++)
                Cout[(size_t)(gm0 + reg) * N + gn] = acc[i][j][reg] + bv;
        }
    }
}

// ---------------- split-K reduce: C = sum_z parts[z] (+bias) ----------------
__global__ __launch_bounds__(256) void reduce_kernel(const float* __restrict__ parts,
                                                     float* __restrict__ C,
                                                     const float* __restrict__ bias,
                                                     long MN, int N, int SK) {
    long i = (long)blockIdx.x * 256 + threadIdx.x;      // float4 index
    if (i * 4 >= MN) return;
    float4 acc = *(const float4*)&parts[i * 4];
    for (int z = 1; z < SK; z++) {
        float4 v = *(const float4*)&parts[(size_t)z * MN + i * 4];
        acc.x += v.x; acc.y += v.y; acc.z += v.z; acc.w += v.w;
    }
    if (bias) {
        int col = (int)((i * 4) % N);
        float4 bv = *(const float4*)&bias[col];
        acc.x += bv.x; acc.y += bv.y; acc.z += bv.z; acc.w += bv.w;
    }
    *(float4*)&C[i * 4] = acc;
}

// ---------------- causal depthwise conv (DCONV=4) + SiLU ----------------
__global__ __launch_bounds__(256) void conv_silu_kernel(const float* __restrict__ xz,
                                                        const float* __restrict__ cw,
                                                        const float* __restrict__ cb,
                                                        float* __restrict__ xc) {
    size_t idx = (size_t)blockIdx.x * 256 + threadIdx.x;
    if (idx >= (size_t)RTOT * DINNER) return;
    int e = (int)(idx % DINNER);
    size_t r = idx / DINNER;
    int l = (int)(r % NP);
    size_t b = r / NP;
    const float* w = cw + (size_t)e * DCONV;
    float acc = cb[e];
#pragma unroll
    for (int k = 0; k < DCONV; k++) {
        int ls = l + k - (DCONV - 1);
        if (ls >= 0) acc += xz[(b * NP + ls) * 768 + e] * w[k];
    }
    xc[idx] = acc / (1.f + __expf(-acc));   // silu (fast exp)
}

// ---------------- dt projection + softplus ----------------
// Writes dt into the DEAD xs-half of xz (cols [0,384), row stride 768).
__global__ __launch_bounds__(256) void dt_kernel(const float* __restrict__ proj,
                                                 const float* __restrict__ dtw,
                                                 const float* __restrict__ dtb,
                                                 float* __restrict__ xz) {
    int idx = blockIdx.x * 256 + threadIdx.x;
    if (idx >= RTOT * DINNER) return;
    int d = idx % DINNER;
    size_t r = (size_t)idx / DINNER;
    const float* pr = proj + r * 44;
    const float* w = dtw + (size_t)d * DTR;
    float acc = dtb[d];
#pragma unroll
    for (int k = 0; k < DTR; k++) acc += pr[k] * w[k];
    // softplus via fast exp/log (guarded: acc>20 -> identity)
    xz[r * 768 + d] = (acc > 20.f) ? acc : __logf(1.f + __expf(acc));
}

// ---------------- chunked selective scan: lane owns (b,d), 16 states in regs ----------------
__global__ __launch_bounds__(128) void scanA_kernel(const float* __restrict__ xc,
                                                    const float* __restrict__ proj,
                                                    const float* __restrict__ xz,
                                                    const float* __restrict__ A_log,
                                                    float* __restrict__ hEnd,
                                                    float* __restrict__ prodDA) {
    int d = blockIdx.x * 128 + threadIdx.x;       // grid.x = 3
    int c = blockIdx.y, b = blockIdx.z;
    float a[DSTATE], h[DSTATE], p[DSTATE];
#pragma unroll
    for (int s = 0; s < DSTATE; s++) {
        a[s] = -expf(A_log[(size_t)d * DSTATE + s]);   // precise (once per lane)
        h[s] = 0.f;
        p[s] = 1.f;
    }
    size_t rbase = (size_t)b * NP + (size_t)c * LC;
    for (int l = 0; l < LC; l++) {
        size_t r = rbase + l;
        float dtv = xz[r * 768 + d];              // dt (stored in xs-half)
        float du = dtv * xc[r * DINNER + d];
        const float* pb = proj + r * 44 + DTR;    // wave-uniform
        float Bv[DSTATE];
        *(float4*)&Bv[0]  = *(const float4*)&pb[0];
        *(float4*)&Bv[4]  = *(const float4*)&pb[4];
        *(float4*)&Bv[8]  = *(const float4*)&pb[8];
        *(float4*)&Bv[12] = *(const float4*)&pb[12];
#pragma unroll
        for (int s = 0; s < DSTATE; s++) {
            float dA = __expf(dtv * a[s]);        // fast exp (hot loop)
            h[s] = h[s] * dA + du * Bv[s];
            p[s] *= dA;
        }
    }
    float* he = hEnd   + (((size_t)b * CHUNKS + c) * DINNER + d) * DSTATE;
    float* pd = prodDA + (((size_t)b * CHUNKS + c) * DINNER + d) * DSTATE;
#pragma unroll
    for (int g = 0; g < 4; g++) {
        *(float4*)&he[g * 4] = *(float4*)&h[g * 4];
        *(float4*)&pd[g * 4] = *(float4*)&p[g * 4];
    }
}

__global__ __launch_bounds__(256) void scanB_kernel(const float* __restrict__ hEnd,
                                                    float* __restrict__ prodDA) {
    int idx = blockIdx.x * 256 + threadIdx.x;
    if (idx >= BB * DINNER * DSTATE) return;
    int b = idx / (DINNER * DSTATE);
    int rem = idx % (DINNER * DSTATE);
    float run = 0.f;
    for (int c = 0; c < CHUNKS; c++) {
        size_t off = ((size_t)b * CHUNKS + c) * (DINNER * DSTATE) + rem;
        float p = prodDA[off];
        float e = hEnd[off];
        prodDA[off] = run;          // hInit for chunk c
        run = run * p + e;
    }
}

__global__ __launch_bounds__(128) void scanC_kernel(const float* __restrict__ xc,
                                                    const float* __restrict__ proj,
                                                    const float* __restrict__ hInit,
                                                    const float* __restrict__ A_log,
                                                    const float* __restrict__ Dv,
                                                    float* __restrict__ xz) {
    int d = blockIdx.x * 128 + threadIdx.x;       // grid.x = 3
    int c = blockIdx.y, b = blockIdx.z;
    float a[DSTATE], h[DSTATE];
#pragma unroll
    for (int s = 0; s < DSTATE; s++)
        a[s] = -expf(A_log[(size_t)d * DSTATE + s]);   // precise (once per lane)
    const float* hi = hInit + (((size_t)b * CHUNKS + c) * DINNER + d) * DSTATE;
#pragma unroll
    for (int g = 0; g < 4; g++)
        *(float4*)&h[g * 4] = *(const float4*)&hi[g * 4];
    float Dd = Dv[d];
    size_t rbase = (size_t)b * NP + (size_t)c * LC;
    for (int l = 0; l < LC; l++) {
        size_t r = rbase + l;
        float dtv = xz[r * 768 + d];              // dt (stored in xs-half)
        float u = xc[r * DINNER + d];
        float du = dtv * u;
        const float* pb = proj + r * 44 + DTR;              // wave-uniform
        const float* pc = proj + r * 44 + DTR + DSTATE;
        float Bv[DSTATE], Cv[DSTATE];
        *(float4*)&Bv[0]  = *(const float4*)&pb[0];
        *(float4*)&Bv[4]  = *(const float4*)&pb[4];
        *(float4*)&Bv[8]  = *(const float4*)&pb[8];
        *(float4*)&Bv[12] = *(const float4*)&pb[12];
        *(float4*)&Cv[0]  = *(const float4*)&pc[0];
        *(float4*)&Cv[4]  = *(const float4*)&pc[4];
        *(float4*)&Cv[8]  = *(const float4*)&pc[8];
        *(float4*)&Cv[12] = *(const float4*)&pc[12];
        float y = 0.f;
#pragma unroll
        for (int s = 0; s < DSTATE; s++) {
            float dA = __expf(dtv * a[s]);        // fast exp (hot loop)
            h[s] = h[s] * dA + du * Bv[s];
            y = fmaf(h[s], Cv[s], y);
        }
        float z = xz[r * 768 + DINNER + d];
        xz[r * 768 + d] = (y + u * Dd) * (z / (1.f + __expf(-z)));
    }
}

// ---------------- final layernorm: per-row stats ----------------
__global__ __launch_bounds__(256) void ln_stats_kernel(const float* __restrict__ x,
                                                       float* __restrict__ stats) {
    int r = blockIdx.x * 4 + (threadIdx.x >> 6);
    int lane = threadIdx.x & 63;
    if (r >= RTOT) return;
    float s = 0.f, ss = 0.f;
    for (int c = lane; c < DM; c += 64) {
        float v = x[(size_t)r * DM + c];
        s += v;
        ss += v * v;
    }
#pragma unroll
    for (int o = 32; o > 0; o >>= 1) {
        s += __shfl_down(s, o);
        ss += __shfl_down(ss, o);
    }
    if (lane == 0) {
        float mu = s / (float)DM;
        float var = ss / (float)DM - mu * mu;
        stats[r * 2] = mu;
        stats[r * 2 + 1] = rsqrtf(var + 1e-5f);
    }
}

// ---------------- normalized mean over sequence ----------------
__global__ __launch_bounds__(256) void ln_mean_kernel(const float* __restrict__ x,
                                                      const float* __restrict__ stats,
                                                      const float* __restrict__ nw,
                                                      const float* __restrict__ nb,
                                                      float* __restrict__ out) {
    int idx = blockIdx.x * 256 + threadIdx.x;
    if (idx >= BB * DM) return;
    int c = idx % DM;
    int b = idx / DM;
    float acc = 0.f;
    for (int l = 0; l < NP; l++) {
        size_t r = (size_t)b * NP + l;
        acc += (x[r * DM + c] - stats[r * 2]) * stats[r * 2 + 1];
    }
    out[idx] = acc * (1.f / (float)NP) * nw[c] + nb[c];
}

extern "C" void kernel_launch(void* const* d_in, const int* in_sizes, int n_in,
                              void* d_out, int out_size, void* d_ws, size_t ws_size,
                              hipStream_t stream) {
    const float* img     = (const float*)d_in[0];
    const float* patch_w = (const float*)d_in[1];
    const float* patch_b = (const float*)d_in[2];
    const float* in_w    = (const float*)d_in[3];
    const float* conv_w  = (const float*)d_in[4];
    const float* conv_b  = (const float*)d_in[5];
    const float* xpw     = (const float*)d_in[6];
    const float* dtw     = (const float*)d_in[7];
    const float* dtb     = (const float*)d_in[8];
    const float* A_log   = (const float*)d_in[9];
    const float* Dv      = (const float*)d_in[10];
    const float* outw    = (const float*)d_in[11];
    const float* norm_w  = (const float*)d_in[12];
    const float* norm_b  = (const float*)d_in[13];
    float* out = (float*)d_out;

    float* ws = (float*)d_ws;
    const size_t R = RTOT;
    float* xA      = ws;                   // R*192
    float* xB      = xA + R * DM;          // R*192
    float* xz      = xB + R * DM;          // R*768  (xs | z; dt then y2 overwrite xs half)
    float* xc      = xz + R * 768;         // R*384
    float* proj    = xc + R * DINNER;      // R*44
    float* scratch = proj + R * 44;        // shared: split-K partials (<=9.64M) OR hEnd+prodDA (11.01M)
    float* hEnd    = scratch;                                        // B*CHUNKS*384*16 = 5.505M
    float* prodDA  = hEnd + (size_t)BB * CHUNKS * DINNER * DSTATE;   // same (becomes hInit)
    float* stats   = scratch + (size_t)2 * BB * CHUNKS * DINNER * DSTATE;   // R*2

    // patch embed: im2col + split-K MFMA GEMM + reduce(+bias)  M=12544, N=192, K=768, SK=4
    {
        size_t n = R * 768;
        im2col_kernel<<<dim3((unsigned)((n + 255) / 256)), 256, 0, stream>>>(img, xz);
        gemm_mfma_kernel<64><<<dim3(3, RTOT / 128, 4), 256, 0, stream>>>(
            xz, 768, patch_w, scratch, nullptr, RTOT, DM, 768, 192);
        long MN = (long)RTOT * DM;
        reduce_kernel<<<dim3((unsigned)((MN / 4 + 255) / 256)), 256, 0, stream>>>(
            scratch, xA, patch_b, MN, DM, 4);
    }

    float* xin = xA;
    float* xout = xB;
    for (int layer = 0; layer < DEPTH; layer++) {
        const float* in_w_l  = in_w + (size_t)layer * 2 * DINNER * DM;
        const float* conv_wl = conv_w + (size_t)layer * DINNER * DCONV;
        const float* conv_bl = conv_b + (size_t)layer * DINNER;
        const float* xpw_l   = xpw + (size_t)layer * (DTR + 2 * DSTATE) * DINNER;
        const float* dtw_l   = dtw + (size_t)layer * DINNER * DTR;
        const float* dtb_l   = dtb + (size_t)layer * DINNER;
        const float* Alog_l  = A_log + (size_t)layer * DINNER * DSTATE;
        const float* Dv_l    = Dv + (size_t)layer * DINNER;
        const float* outw_l  = outw + (size_t)layer * DM * DINNER;

        // xz = x @ in_w^T   (M=12544, N=768, K=192) — direct, 588 blocks
        gemm_mfma_kernel<128><<<dim3(768 / 128, RTOT / 128, 1), 256, 0, stream>>>(
            xin, DM, in_w_l, xz, nullptr, RTOT, 2 * DINNER, DM, DM);
        // xc = silu(causal depthwise conv(xs))
        {
            size_t n = R * DINNER;
            conv_silu_kernel<<<dim3((unsigned)((n + 255) / 256)), 256, 0, stream>>>(
                xz, conv_wl, conv_bl, xc);
        }
        // proj = xc @ xpw^T   (M=12544, N=44, K=384) SK=4, Kc=96
        gemm_mfma_kernel<64><<<dim3(1, RTOT / 128, 4), 256, 0, stream>>>(
            xc, DINNER, xpw_l, scratch, nullptr, RTOT, DTR + 2 * DSTATE, DINNER, 96);
        {
            long MN = (long)RTOT * 44;
            reduce_kernel<<<dim3((unsigned)((MN / 4 + 255) / 256)), 256, 0, stream>>>(
                scratch, proj, nullptr, MN, 44, 4);
        }
        // dt = softplus(proj[:, :12] @ dtw^T + dtb) -> xz xs-half
        dt_kernel<<<dim3((RTOT * DINNER + 255) / 256), 256, 0, stream>>>(
            proj, dtw_l, dtb_l, xz);
        // chunked scan: A (local), B (combine), C (apply + epilogue -> xz xs-half)
        scanA_kernel<<<dim3(3, CHUNKS, BB), 128, 0, stream>>>(
            xc, proj, xz, Alog_l, hEnd, prodDA);
        scanB_kernel<<<dim3((BB * DINNER * DSTATE + 255) / 256), 256, 0, stream>>>(
            hEnd, prodDA);
        scanC_kernel<<<dim3(3, CHUNKS, BB), 128, 0, stream>>>(
            xc, proj, prodDA, Alog_l, Dv_l, xz);
        // x_next = y2 @ outw^T   (M=12544, N=192, K=384; A = xz lda=768) SK=3, Kc=128
        gemm_mfma_kernel<64><<<dim3(DM / 64, RTOT / 128, 3), 256, 0, stream>>>(
            xz, 768, outw_l, scratch, nullptr, RTOT, DM, DINNER, 128);
        {
            long MN = (long)RTOT * DM;
            reduce_kernel<<<dim3((unsigned)((MN / 4 + 255) / 256)), 256, 0, stream>>>(
                scratch, xout, nullptr, MN, DM, 3);
        }

        float* t = xin; xin = xout; xout = t;
    }

    // final layernorm + mean over sequence
    ln_stats_kernel<<<dim3(RTOT / 4), 256, 0, stream>>>(xin, stats);
    ln_mean_kernel<<<dim3((BB * DM + 255) / 256), 256, 0, stream>>>(
        xin, stats, norm_w, norm_b, out);
}